// Round 17
// baseline (1976.777 us; speedup 1.0000x reference)
//
#include <hip/hip_runtime.h>

typedef float f32x4 __attribute__((ext_vector_type(4)));
typedef int i32x4 __attribute__((ext_vector_type(4)));

#define B_ 256
#define T_ 1024
#define H_ 512
#define E_ 256
#define O_ 256
#define V_ 256

// Prepped operands in device globals: graph-safe, rewritten every launch.
__device__ __align__(16) int g_P3[V_ * H_];               // P pre-quantized: U = round(P*127/s_n) (512 KB)
__device__ __align__(16) signed char    g_Whq[H_ * H_];   // Wh int8, K=64 frag layout (256 KB)
__device__ float                        g_scale[H_];      // per-row Wh quant scale s_n
__device__ __align__(16) signed char    g_Wdq[O_ * H_];   // Wd int8, K=64 frag layout (128 KB)
__device__ float                        g_sd[O_];         // per-row Wd quant scale

__device__ __forceinline__ unsigned short f2bf(float f) {
    union { float f; unsigned int u; } v; v.f = f;
    unsigned int r = v.u + 0x7fffu + ((v.u >> 16) & 1u);   // RNE
    return (unsigned short)(r >> 16);
}
// 16-B-aligned row swizzle (b128-safe)
#define SW16(r_) (((r_) & 15) << 4)

// ---------------- K1b: Wh -> int8 + per-row scale, K=64 frag layout ----------------
// Tile (ntile, ktt): 1024 B; byte j of lane l = W[n=ntile*16+(l&15)][k=ktt*64+(l>>4)*16+j].
// A-image reads use the SAME k-order -> correct for any hw (lane,elem)->k mapping.
__global__ void k_prep8(const float* __restrict__ W) {
    const int n = blockIdx.x;
    const int li = threadIdx.x;                  // covers k = li*8 .. li*8+7
    const float* src = W + (size_t)n * (E_ + H_) + E_;   // Wh row n = W[n][256:768]
    float v[8];
    float mx = 0.f;
#pragma unroll
    for (int m = 0; m < 8; m++) { v[m] = src[li * 8 + m]; mx = fmaxf(mx, fabsf(v[m])); }
#pragma unroll
    for (int off = 1; off < 64; off <<= 1)
        mx = fmaxf(mx, __shfl_xor(mx, off));
    const float s = fmaxf(mx, 1e-20f) / 127.f;
    if (li == 0) g_scale[n] = s;
    const float inv = 1.f / s;
    unsigned long long pk = 0;
#pragma unroll
    for (int m = 0; m < 8; m++) {
        int q = __float2int_rn(v[m] * inv);
        q = q > 127 ? 127 : (q < -127 ? -127 : q);
        pk |= ((unsigned long long)(unsigned char)(signed char)q) << (8 * m);
    }
    const int ktt = li >> 3;                     // k/64
    const int hig = (li >> 1) & 3;               // (k&63)/16
    const int jh = li & 1;                       // byte-half within the 16
    *(unsigned long long*)(g_Whq + (((size_t)(n >> 4) * 8 + ktt) * 1024)
                           + ((n & 15) + (hig << 4)) * 16 + jh * 8) = pk;
}

// ---------------- K1c: Wd -> int8 + per-row scale, K=64 frag layout ----------------
__global__ void k_prepWd8(const float* __restrict__ Wd) {
    const int n = blockIdx.x;
    const int li = threadIdx.x;
    const float* src = Wd + (size_t)n * H_;
    float v[8];
    float mx = 0.f;
#pragma unroll
    for (int m = 0; m < 8; m++) { v[m] = src[li * 8 + m]; mx = fmaxf(mx, fabsf(v[m])); }
#pragma unroll
    for (int off = 1; off < 64; off <<= 1)
        mx = fmaxf(mx, __shfl_xor(mx, off));
    const float s = fmaxf(mx, 1e-20f) / 127.f;
    if (li == 0) g_sd[n] = s;
    const float inv = 1.f / s;
    unsigned long long pk = 0;
#pragma unroll
    for (int m = 0; m < 8; m++) {
        int q = __float2int_rn(v[m] * inv);
        q = q > 127 ? 127 : (q < -127 ? -127 : q);
        pk |= ((unsigned long long)(unsigned char)(signed char)q) << (8 * m);
    }
    const int ktt = li >> 3;
    const int hig = (li >> 1) & 3;
    const int jh = li & 1;
    *(unsigned long long*)(g_Wdq + (((size_t)(n >> 4) * 8 + ktt) * 1024)
                           + ((n & 15) + (hig << 4)) * 16 + jh * 8) = pk;
}

// ---------------- K1a: P3 = round((b + emb @ Wx^T) * 127 / s_n) ----------------
// Runs AFTER k_prep8 (reads g_scale). Layout: slot v*512 + w*64 + lo*4 + nt —
// the 4 nt values per (row, wave, lo) are one uint4 -> one dwordx4 load in k_rnn.
__global__ void k_embWx(const float* __restrict__ emb, const float* __restrict__ W,
                        const float* __restrict__ bb) {
    __shared__ float e[E_];
    int v = blockIdx.x;
    e[threadIdx.x] = emb[(size_t)v * E_ + threadIdx.x];
    __syncthreads();
#pragma unroll
    for (int rep = 0; rep < 2; rep++) {
        int n = threadIdx.x + rep * 256;
        const float4* wr4 = (const float4*)(W + (size_t)n * (E_ + H_));
        float s = bb[n];
        for (int k = 0; k < E_ / 4; k++) {
            float4 wv = wr4[k];
            s += e[4*k] * wv.x + e[4*k+1] * wv.y + e[4*k+2] * wv.z + e[4*k+3] * wv.w;
        }
        int w = n >> 6, r6 = n & 63;
        int lo = r6 & 15, nt = r6 >> 4;
        g_P3[v * 512 + w * 64 + lo * 4 + nt] =
            __float2int_rn(s * 127.f / g_scale[n]);
    }
}

// ---------------- K2: recurrence — K=64 i8, u in C-operand, Padé tanh ----------------
// 16 blocks x 16 rows; 512 thr = 8 waves; wave owns ntiles 4w..4w+3.
// vs R16: (1) u folded into MFMA C-init as pre-quantized i32 (g_P3, prefetched one
// step ahead like xs) — kills the bf16 unpack+add in the epilogue; (2) tanh via
// Padé-CF(5) rational f(945+105u+u^2)/(945+420u+15u^2), f clamped ±4: 1 trans
// (rcp) instead of 2 (exp+rcp) — R16 PMC showed the 32 trans/wave-step were
// ~1150 cy/SIMD, the biggest line item. Max err 2.3e-3 only in the q=127
// saturation zone; mid-range <5e-4 (0.06 q-units). ONE lgkm-only barrier.
__global__ void __launch_bounds__(512) k_rnn(const int* __restrict__ x,
                                             const float* __restrict__ h0,
                                             float* __restrict__ out) {
    __shared__ __align__(16) signed char lds_img[2][16 * 512];    // 16 KB dbuf
    __shared__ __align__(16) signed char lds_W[128 * 1024];       // 128 KB ktt 4..7
    const int tid = threadIdx.x;
    const int w = tid >> 6, l = tid & 63;
    const int hi = l >> 4, lo = l & 15;
    const int r0 = blockIdx.x * 16;
    const int w4 = w * 4;
    const int nb = w * 64 + lo;                 // n = nb + nt*16
    const int swl = SW16(lo);                   // A-read swizzle

    // pinned B-frags ktt 0..3 (4 nt x 4 ktt x 16 B = 64 VGPRs)
    i32x4 breg[4][4];
#pragma unroll
    for (int nt = 0; nt < 4; nt++)
#pragma unroll
        for (int kt = 0; kt < 4; kt++)
            breg[nt][kt] = *(const i32x4*)(g_Whq + ((w4 + nt) * 8 + kt) * 1024 + l * 16);

    // LDS-resident B-frags ktt 4..7 (32 ntiles x 4 ktt x 1 KB = 128 KB)
#pragma unroll
    for (int nt = 0; nt < 4; nt++)
#pragma unroll
        for (int kk = 0; kk < 4; kk++) {
            i32x4 v = *(const i32x4*)(g_Whq + ((w4 + nt) * 8 + 4 + kk) * 1024 + l * 16);
            *(i32x4*)(lds_W + ((w4 + nt) * 4 + kk) * 1024 + l * 16) = v;
        }

    // per-output scales: gs[nt] = s_n / 127
    float gs[4];
#pragma unroll
    for (int nt = 0; nt < 4; nt++) gs[nt] = g_scale[nb + nt * 16] * (1.f / 127.f);

    // stage h0 -> image 0 (f32 -> i8, SW16-swizzled, one uint4/thread)
    {
        const int row = tid >> 5;
        const int c0 = (tid & 31) * 16;
        const float* hp = h0 + (size_t)(r0 + row) * H_ + c0;
        union { unsigned char b[16]; uint4 v; } pk;
#pragma unroll
        for (int i = 0; i < 16; i++) {
            int qq = __float2int_rn(fminf(fmaxf(hp[i], -1.f), 1.f) * 127.f);
            pk.b[i] = (unsigned char)(signed char)qq;
        }
        *(uint4*)(lds_img[0] + row * 512 + (c0 ^ SW16(row))) = pk.v;
    }

    // x + U prefetch for t=0 (thread's 4 batch rows r = hi*4+rg)
    const int xr = r0 + hi * 4;
    const int p3b = (w << 6) + (lo << 2);
    int xs0 = x[(xr + 0) * T_], xs1 = x[(xr + 1) * T_],
        xs2 = x[(xr + 2) * T_], xs3 = x[(xr + 3) * T_];
    i32x4 u40 = *(const i32x4*)(g_P3 + (xs0 << 9) + p3b);
    i32x4 u41 = *(const i32x4*)(g_P3 + (xs1 << 9) + p3b);
    i32x4 u42 = *(const i32x4*)(g_P3 + (xs2 << 9) + p3b);
    i32x4 u43 = *(const i32x4*)(g_P3 + (xs3 << 9) + p3b);

    unsigned char* hsb = (unsigned char*)out;    // hs i8 in-place (1024-B row stride)
    float* hfin = out + (size_t)B_ * T_ * O_;
    __syncthreads();

#pragma unroll 1
    for (int t = 0; t < T_; t++) {
        const signed char* img = lds_img[t & 1];

        // coalesced hs write of h_{t-1} from the fresh image
        if (t) {
            const int row = tid >> 5;
            const int cb = (tid & 31) * 16;
            uint4 d = *(const uint4*)(img + row * 512 + (cb ^ SW16(row)));
            *(uint4*)(hsb + (size_t)(r0 + row) * (T_ * 1024) + (size_t)(t - 1) * 1024 + cb) = d;
        }

        // acc C-init carries U(t)  (acc[nt][rg] = u4<rg>[nt])
        i32x4 acc[4];
#pragma unroll
        for (int nt = 0; nt < 4; nt++) {
            acc[nt][0] = u40[nt]; acc[nt][1] = u41[nt];
            acc[nt][2] = u42[nt]; acc[nt][3] = u43[nt];
        }
        // prefetch x(t+1) then U(t+1) (full-step latency cover)
        {
            const int tn = (t < T_ - 1) ? t + 1 : t;
            xs0 = x[(xr + 0) * T_ + tn]; xs1 = x[(xr + 1) * T_ + tn];
            xs2 = x[(xr + 2) * T_ + tn]; xs3 = x[(xr + 3) * T_ + tn];
            u40 = *(const i32x4*)(g_P3 + (xs0 << 9) + p3b);
            u41 = *(const i32x4*)(g_P3 + (xs1 << 9) + p3b);
            u42 = *(const i32x4*)(g_P3 + (xs2 << 9) + p3b);
            u43 = *(const i32x4*)(g_P3 + (xs3 << 9) + p3b);
        }

        // MFMA K=64: 32 per wave (8 ktt x 4 nt), 8-deep chains
#pragma unroll
        for (int kt = 0; kt < 4; kt++) {
            i32x4 a = *(const i32x4*)(img + lo * 512 + ((kt * 64 + hi * 16) ^ swl));
            acc[0] = __builtin_amdgcn_mfma_i32_16x16x64_i8(a, breg[0][kt], acc[0], 0, 0, 0);
            acc[1] = __builtin_amdgcn_mfma_i32_16x16x64_i8(a, breg[1][kt], acc[1], 0, 0, 0);
            acc[2] = __builtin_amdgcn_mfma_i32_16x16x64_i8(a, breg[2][kt], acc[2], 0, 0, 0);
            acc[3] = __builtin_amdgcn_mfma_i32_16x16x64_i8(a, breg[3][kt], acc[3], 0, 0, 0);
        }
#pragma unroll
        for (int kk = 0; kk < 4; kk++) {
            i32x4 a = *(const i32x4*)(img + lo * 512 + (((4 + kk) * 64 + hi * 16) ^ swl));
            i32x4 b0 = *(const i32x4*)(lds_W + ((w4 + 0) * 4 + kk) * 1024 + l * 16);
            i32x4 b1 = *(const i32x4*)(lds_W + ((w4 + 1) * 4 + kk) * 1024 + l * 16);
            i32x4 b2 = *(const i32x4*)(lds_W + ((w4 + 2) * 4 + kk) * 1024 + l * 16);
            i32x4 b3 = *(const i32x4*)(lds_W + ((w4 + 3) * 4 + kk) * 1024 + l * 16);
            acc[0] = __builtin_amdgcn_mfma_i32_16x16x64_i8(a, b0, acc[0], 0, 0, 0);
            acc[1] = __builtin_amdgcn_mfma_i32_16x16x64_i8(a, b1, acc[1], 0, 0, 0);
            acc[2] = __builtin_amdgcn_mfma_i32_16x16x64_i8(a, b2, acc[2], 0, 0, 0);
            acc[3] = __builtin_amdgcn_mfma_i32_16x16x64_i8(a, b3, acc[3], 0, 0, 0);
        }

        // epilogue: f = acc*gs (clamped ±4); q = round(127*Pade5(f)); 1 trans only
        signed char* imw = lds_img[(t & 1) ^ 1];
#pragma unroll
        for (int nt = 0; nt < 4; nt++) {
            const int nn = nb + nt * 16;
#pragma unroll
            for (int rg = 0; rg < 4; rg++) {
                const int r = hi * 4 + rg;       // C/D row = (lane>>4)*4 + reg [m89]
                float f = (float)acc[nt][rg] * gs[nt];
                f = fminf(fmaxf(f, -4.f), 4.f);
                float uu = f * f;
                float np = __builtin_fmaf(uu, uu + 105.f, 945.f);
                float num = f * np;
                float dp = __builtin_fmaf(uu, 15.f, 420.f);
                float den = __builtin_fmaf(uu, dp, 945.f);
                float r1; asm("v_rcp_f32 %0, %1" : "=v"(r1) : "v"(den));
                float th = num * r1;             // tanh(f), err <= 2.3e-3 (sat zone)
                int q = __float2int_rn(th * 127.f);
                imw[r * 512 + (nn ^ SW16(r))] = (signed char)q;
                if (t == T_ - 1) hfin[(r0 + r) * H_ + nn] = th;
            }
        }

        // single barrier: LDS visibility only (global stores fly freely)
        __builtin_amdgcn_sched_barrier(0);
        asm volatile("s_waitcnt lgkmcnt(0)" ::: "memory");
        __builtin_amdgcn_s_barrier();
        __builtin_amdgcn_sched_barrier(0);
    }

    // tail: hs[:, T-1] coalesced from image[0]
    {
        const int row = tid >> 5;
        const int cb = (tid & 31) * 16;
        uint4 d = *(const uint4*)(lds_img[0] + row * 512 + (cb ^ SW16(row)));
        *(uint4*)(hsb + (size_t)(r0 + row) * (T_ * 1024) + (size_t)(T_ - 1) * 1024 + cb) = d;
    }
}

// ---------------- K3: outputs = (hs-i8) @ (Wd-i8)^T * scales + bd, in-place ----------------
__launch_bounds__(512, 2)
__global__ void k_out(const float* __restrict__ bd, float* out) {
    int tid = threadIdx.x;
    int w = tid >> 6, l = tid & 63;
    int hi = l >> 4, lo = l & 15;
    size_t m0 = (size_t)blockIdx.x * 256 + w * 32;
    const unsigned char* hsb = (const unsigned char*)out;
    float bdv[16], sdl[16];
#pragma unroll
    for (int nt = 0; nt < 16; nt++) {
        bdv[nt] = bd[nt * 16 + lo];
        sdl[nt] = g_sd[nt * 16 + lo] * (1.f / 127.f);
    }
    i32x4 acc[2][16];
#pragma unroll
    for (int m = 0; m < 2; m++)
#pragma unroll
        for (int nt = 0; nt < 16; nt++) { acc[m][nt][0] = 0; acc[m][nt][1] = 0; acc[m][nt][2] = 0; acc[m][nt][3] = 0; }
#pragma unroll 2
    for (int kt = 0; kt < 8; kt++) {
        i32x4 a0 = *(const i32x4*)(hsb + (m0 + lo) * 1024 + kt * 64 + hi * 16);
        i32x4 a1 = *(const i32x4*)(hsb + (m0 + 16 + lo) * 1024 + kt * 64 + hi * 16);
#pragma unroll
        for (int nt = 0; nt < 16; nt++) {
            i32x4 bf = *(const i32x4*)(g_Wdq + (nt * 8 + kt) * 1024 + l * 16);
            acc[0][nt] = __builtin_amdgcn_mfma_i32_16x16x64_i8(a0, bf, acc[0][nt], 0, 0, 0);
            acc[1][nt] = __builtin_amdgcn_mfma_i32_16x16x64_i8(a1, bf, acc[1][nt], 0, 0, 0);
        }
    }
#pragma unroll
    for (int m = 0; m < 2; m++)
#pragma unroll
        for (int nt = 0; nt < 16; nt++)
#pragma unroll
            for (int rg = 0; rg < 4; rg++) {
                size_t row = m0 + m * 16 + hi * 4 + rg;
                out[row * O_ + nt * 16 + lo] = (float)acc[m][nt][rg] * sdl[nt] + bdv[nt];
            }
}

extern "C" void kernel_launch(void* const* d_in, const int* in_sizes, int n_in,
                              void* d_out, int out_size, void* d_ws, size_t ws_size,
                              hipStream_t stream) {
    const int*   x   = (const int*)d_in[0];
    const float* h0  = (const float*)d_in[1];
    const float* emb = (const float*)d_in[2];
    const float* W   = (const float*)d_in[3];
    const float* b   = (const float*)d_in[4];
    const float* Wd  = (const float*)d_in[5];
    const float* bd  = (const float*)d_in[6];
    float* out = (float*)d_out;

    k_prep8<<<dim3(H_), dim3(64), 0, stream>>>(W);
    k_prepWd8<<<dim3(O_), dim3(64), 0, stream>>>(Wd);
    k_embWx<<<dim3(V_), dim3(256), 0, stream>>>(emb, W, b);   // after k_prep8 (g_scale)
    k_rnn<<<dim3(16), dim3(512), 0, stream>>>(x, h0, out);
    k_out<<<dim3(1024), dim3(512), 0, stream>>>(bd, out);
}

// Round 18
// 1921.151 us; speedup vs baseline: 1.0290x; 1.0290x over previous
//
#include <hip/hip_runtime.h>

typedef float f32x4 __attribute__((ext_vector_type(4)));
typedef int i32x4 __attribute__((ext_vector_type(4)));

#define B_ 256
#define T_ 1024
#define H_ 512
#define E_ 256
#define O_ 256
#define V_ 256

// Prepped operands in device globals: graph-safe, rewritten every launch.
__device__ __align__(16) int g_P3[V_ * H_];               // U = round(P*127/s_n) (512 KB)
__device__ __align__(16) signed char    g_Whq[H_ * H_];   // Wh int8, K=64 frag layout (256 KB)
__device__ float                        g_scale[H_];      // per-row Wh quant scale s_n
__device__ __align__(16) signed char    g_Wdq[O_ * H_];   // Wd int8, K=64 frag layout (128 KB)
__device__ float                        g_sd[O_];         // per-row Wd quant scale

// 16-B-aligned row swizzle (b128-safe)
#define SW16(r_) (((r_) & 15) << 4)

// ---------------- K1b: Wh -> int8 + per-row scale, K=64 frag layout ----------------
// Tile (ntile, ktt): 1024 B; byte j of lane l = W[n=ntile*16+(l&15)][k=ktt*64+(l>>4)*16+j].
// A-image reads use the SAME k-order -> correct for any hw (lane,elem)->k mapping.
__global__ void k_prep8(const float* __restrict__ W) {
    const int n = blockIdx.x;
    const int li = threadIdx.x;                  // covers k = li*8 .. li*8+7
    const float* src = W + (size_t)n * (E_ + H_) + E_;   // Wh row n = W[n][256:768]
    float v[8];
    float mx = 0.f;
#pragma unroll
    for (int m = 0; m < 8; m++) { v[m] = src[li * 8 + m]; mx = fmaxf(mx, fabsf(v[m])); }
#pragma unroll
    for (int off = 1; off < 64; off <<= 1)
        mx = fmaxf(mx, __shfl_xor(mx, off));
    const float s = fmaxf(mx, 1e-20f) / 127.f;
    if (li == 0) g_scale[n] = s;
    const float inv = 1.f / s;
    unsigned long long pk = 0;
#pragma unroll
    for (int m = 0; m < 8; m++) {
        int q = __float2int_rn(v[m] * inv);
        q = q > 127 ? 127 : (q < -127 ? -127 : q);
        pk |= ((unsigned long long)(unsigned char)(signed char)q) << (8 * m);
    }
    const int ktt = li >> 3;                     // k/64
    const int hig = (li >> 1) & 3;               // (k&63)/16
    const int jh = li & 1;                       // byte-half within the 16
    *(unsigned long long*)(g_Whq + (((size_t)(n >> 4) * 8 + ktt) * 1024)
                           + ((n & 15) + (hig << 4)) * 16 + jh * 8) = pk;
}

// ---------------- K1c: Wd -> int8 + per-row scale, K=64 frag layout ----------------
__global__ void k_prepWd8(const float* __restrict__ Wd) {
    const int n = blockIdx.x;
    const int li = threadIdx.x;
    const float* src = Wd + (size_t)n * H_;
    float v[8];
    float mx = 0.f;
#pragma unroll
    for (int m = 0; m < 8; m++) { v[m] = src[li * 8 + m]; mx = fmaxf(mx, fabsf(v[m])); }
#pragma unroll
    for (int off = 1; off < 64; off <<= 1)
        mx = fmaxf(mx, __shfl_xor(mx, off));
    const float s = fmaxf(mx, 1e-20f) / 127.f;
    if (li == 0) g_sd[n] = s;
    const float inv = 1.f / s;
    unsigned long long pk = 0;
#pragma unroll
    for (int m = 0; m < 8; m++) {
        int q = __float2int_rn(v[m] * inv);
        q = q > 127 ? 127 : (q < -127 ? -127 : q);
        pk |= ((unsigned long long)(unsigned char)(signed char)q) << (8 * m);
    }
    const int ktt = li >> 3;
    const int hig = (li >> 1) & 3;
    const int jh = li & 1;
    *(unsigned long long*)(g_Wdq + (((size_t)(n >> 4) * 8 + ktt) * 1024)
                           + ((n & 15) + (hig << 4)) * 16 + jh * 8) = pk;
}

// ---------------- K1a: P3 = round((b + emb @ Wx^T) * 127 / s_n) ----------------
// Runs AFTER k_prep8 (reads g_scale). Layout: slot v*512 + w*64 + lo*4 + nt —
// the 4 nt values per (row, wave, lo) are one uint4 -> one dwordx4 load in k_rnn.
__global__ void k_embWx(const float* __restrict__ emb, const float* __restrict__ W,
                        const float* __restrict__ bb) {
    __shared__ float e[E_];
    int v = blockIdx.x;
    e[threadIdx.x] = emb[(size_t)v * E_ + threadIdx.x];
    __syncthreads();
#pragma unroll
    for (int rep = 0; rep < 2; rep++) {
        int n = threadIdx.x + rep * 256;
        const float4* wr4 = (const float4*)(W + (size_t)n * (E_ + H_));
        float s = bb[n];
        for (int k = 0; k < E_ / 4; k++) {
            float4 wv = wr4[k];
            s += e[4*k] * wv.x + e[4*k+1] * wv.y + e[4*k+2] * wv.z + e[4*k+3] * wv.w;
        }
        int w = n >> 6, r6 = n & 63;
        int lo = r6 & 15, nt = r6 >> 4;
        g_P3[v * 512 + w * 64 + lo * 4 + nt] =
            __float2int_rn(s * 127.f / g_scale[n]);
    }
}

// ---------------- K2: recurrence — K=64 i8, u in C-operand, EXP tanh ----------------
// 16 blocks x 16 rows; 512 thr = 8 waves; wave owns ntiles 4w..4w+3.
// R17 post-mortem: Pade (+7 VALU, -1 trans per output) REGRESSED — trans ops
// co-issue with VALU on a separate pipe and were effectively free; VALU issue is
// the scarce resource. So: R16's exp-form tanh (2 trans + 4 VALU) + R17's u-fold
// (U=round(P*127/s_n) in the i32 C-operand — removes bf16 unpack+add, pure VALU
// cut). Wh: ktt 0..3 in 64 VGPRs, ktt 4..7 in 128 KB LDS; images 2x8 KB;
// ONE lgkm-only barrier; hs written coalesced from the image next step.
__global__ void __launch_bounds__(512) k_rnn(const int* __restrict__ x,
                                             const float* __restrict__ h0,
                                             float* __restrict__ out) {
    __shared__ __align__(16) signed char lds_img[2][16 * 512];    // 16 KB dbuf
    __shared__ __align__(16) signed char lds_W[128 * 1024];       // 128 KB ktt 4..7
    const int tid = threadIdx.x;
    const int w = tid >> 6, l = tid & 63;
    const int hi = l >> 4, lo = l & 15;
    const int r0 = blockIdx.x * 16;
    const int w4 = w * 4;
    const int nb = w * 64 + lo;                 // n = nb + nt*16
    const int swl = SW16(lo);                   // A-read swizzle

    // pinned B-frags ktt 0..3 (4 nt x 4 ktt x 16 B = 64 VGPRs)
    i32x4 breg[4][4];
#pragma unroll
    for (int nt = 0; nt < 4; nt++)
#pragma unroll
        for (int kt = 0; kt < 4; kt++)
            breg[nt][kt] = *(const i32x4*)(g_Whq + ((w4 + nt) * 8 + kt) * 1024 + l * 16);

    // LDS-resident B-frags ktt 4..7 (32 ntiles x 4 ktt x 1 KB = 128 KB)
#pragma unroll
    for (int nt = 0; nt < 4; nt++)
#pragma unroll
        for (int kk = 0; kk < 4; kk++) {
            i32x4 v = *(const i32x4*)(g_Whq + ((w4 + nt) * 8 + 4 + kk) * 1024 + l * 16);
            *(i32x4*)(lds_W + ((w4 + nt) * 4 + kk) * 1024 + l * 16) = v;
        }

    // per-output scales: gs[nt] = s_n / 127
    float gs[4];
#pragma unroll
    for (int nt = 0; nt < 4; nt++) gs[nt] = g_scale[nb + nt * 16] * (1.f / 127.f);

    // stage h0 -> image 0 (f32 -> i8, SW16-swizzled, one uint4/thread)
    {
        const int row = tid >> 5;
        const int c0 = (tid & 31) * 16;
        const float* hp = h0 + (size_t)(r0 + row) * H_ + c0;
        union { unsigned char b[16]; uint4 v; } pk;
#pragma unroll
        for (int i = 0; i < 16; i++) {
            int qq = __float2int_rn(fminf(fmaxf(hp[i], -1.f), 1.f) * 127.f);
            pk.b[i] = (unsigned char)(signed char)qq;
        }
        *(uint4*)(lds_img[0] + row * 512 + (c0 ^ SW16(row))) = pk.v;
    }

    // x + U prefetch for t=0 (thread's 4 batch rows r = hi*4+rg)
    const int xr = r0 + hi * 4;
    const int p3b = (w << 6) + (lo << 2);
    int xs0 = x[(xr + 0) * T_], xs1 = x[(xr + 1) * T_],
        xs2 = x[(xr + 2) * T_], xs3 = x[(xr + 3) * T_];
    i32x4 u40 = *(const i32x4*)(g_P3 + (xs0 << 9) + p3b);
    i32x4 u41 = *(const i32x4*)(g_P3 + (xs1 << 9) + p3b);
    i32x4 u42 = *(const i32x4*)(g_P3 + (xs2 << 9) + p3b);
    i32x4 u43 = *(const i32x4*)(g_P3 + (xs3 << 9) + p3b);

    unsigned char* hsb = (unsigned char*)out;    // hs i8 in-place (1024-B row stride)
    float* hfin = out + (size_t)B_ * T_ * O_;
    __syncthreads();

#pragma unroll 1
    for (int t = 0; t < T_; t++) {
        const signed char* img = lds_img[t & 1];

        // coalesced hs write of h_{t-1} from the fresh image
        if (t) {
            const int row = tid >> 5;
            const int cb = (tid & 31) * 16;
            uint4 d = *(const uint4*)(img + row * 512 + (cb ^ SW16(row)));
            *(uint4*)(hsb + (size_t)(r0 + row) * (T_ * 1024) + (size_t)(t - 1) * 1024 + cb) = d;
        }

        // acc C-init carries U(t)  (acc[nt][rg] = u4<rg>[nt])
        i32x4 acc[4];
#pragma unroll
        for (int nt = 0; nt < 4; nt++) {
            acc[nt][0] = u40[nt]; acc[nt][1] = u41[nt];
            acc[nt][2] = u42[nt]; acc[nt][3] = u43[nt];
        }
        // prefetch x(t+1) then U(t+1) (full-step latency cover)
        {
            const int tn = (t < T_ - 1) ? t + 1 : t;
            xs0 = x[(xr + 0) * T_ + tn]; xs1 = x[(xr + 1) * T_ + tn];
            xs2 = x[(xr + 2) * T_ + tn]; xs3 = x[(xr + 3) * T_ + tn];
            u40 = *(const i32x4*)(g_P3 + (xs0 << 9) + p3b);
            u41 = *(const i32x4*)(g_P3 + (xs1 << 9) + p3b);
            u42 = *(const i32x4*)(g_P3 + (xs2 << 9) + p3b);
            u43 = *(const i32x4*)(g_P3 + (xs3 << 9) + p3b);
        }

        // MFMA K=64: 32 per wave (8 ktt x 4 nt), 8-deep chains
#pragma unroll
        for (int kt = 0; kt < 4; kt++) {
            i32x4 a = *(const i32x4*)(img + lo * 512 + ((kt * 64 + hi * 16) ^ swl));
            acc[0] = __builtin_amdgcn_mfma_i32_16x16x64_i8(a, breg[0][kt], acc[0], 0, 0, 0);
            acc[1] = __builtin_amdgcn_mfma_i32_16x16x64_i8(a, breg[1][kt], acc[1], 0, 0, 0);
            acc[2] = __builtin_amdgcn_mfma_i32_16x16x64_i8(a, breg[2][kt], acc[2], 0, 0, 0);
            acc[3] = __builtin_amdgcn_mfma_i32_16x16x64_i8(a, breg[3][kt], acc[3], 0, 0, 0);
        }
#pragma unroll
        for (int kk = 0; kk < 4; kk++) {
            i32x4 a = *(const i32x4*)(img + lo * 512 + (((4 + kk) * 64 + hi * 16) ^ swl));
            i32x4 b0 = *(const i32x4*)(lds_W + ((w4 + 0) * 4 + kk) * 1024 + l * 16);
            i32x4 b1 = *(const i32x4*)(lds_W + ((w4 + 1) * 4 + kk) * 1024 + l * 16);
            i32x4 b2 = *(const i32x4*)(lds_W + ((w4 + 2) * 4 + kk) * 1024 + l * 16);
            i32x4 b3 = *(const i32x4*)(lds_W + ((w4 + 3) * 4 + kk) * 1024 + l * 16);
            acc[0] = __builtin_amdgcn_mfma_i32_16x16x64_i8(a, b0, acc[0], 0, 0, 0);
            acc[1] = __builtin_amdgcn_mfma_i32_16x16x64_i8(a, b1, acc[1], 0, 0, 0);
            acc[2] = __builtin_amdgcn_mfma_i32_16x16x64_i8(a, b2, acc[2], 0, 0, 0);
            acc[3] = __builtin_amdgcn_mfma_i32_16x16x64_i8(a, b3, acc[3], 0, 0, 0);
        }

        // epilogue: f = acc*gs; q = rndne(127 - 254/(exp2(2log2e*f)+1))
        // (2 trans + 4 VALU per output; trans co-issues — R17 lesson)
        signed char* imw = lds_img[(t & 1) ^ 1];
#pragma unroll
        for (int nt = 0; nt < 4; nt++) {
            const int nn = nb + nt * 16;
#pragma unroll
            for (int rg = 0; rg < 4; rg++) {
                const int r = hi * 4 + rg;       // C/D row = (lane>>4)*4 + reg [m89]
                float f = (float)acc[nt][rg] * gs[nt];
                float kf = f * 2.885390081777927f;
                float E; asm("v_exp_f32 %0, %1" : "=v"(E) : "v"(kf));
                float d1 = E + 1.f;
                float r1; asm("v_rcp_f32 %0, %1" : "=v"(r1) : "v"(d1));
                float qf = __builtin_fmaf(-254.f, r1, 127.f);   // = 127*tanh(f)
                int q = __float2int_rn(qf);
                imw[r * 512 + (nn ^ SW16(r))] = (signed char)q;
                if (t == T_ - 1) hfin[(r0 + r) * H_ + nn] = qf * (1.f / 127.f);
            }
        }

        // single barrier: LDS visibility only (global stores fly freely)
        __builtin_amdgcn_sched_barrier(0);
        asm volatile("s_waitcnt lgkmcnt(0)" ::: "memory");
        __builtin_amdgcn_s_barrier();
        __builtin_amdgcn_sched_barrier(0);
    }

    // tail: hs[:, T-1] coalesced from image[0]
    {
        const int row = tid >> 5;
        const int cb = (tid & 31) * 16;
        uint4 d = *(const uint4*)(lds_img[0] + row * 512 + (cb ^ SW16(row)));
        *(uint4*)(hsb + (size_t)(r0 + row) * (T_ * 1024) + (size_t)(T_ - 1) * 1024 + cb) = d;
    }
}

// ---------------- K3: outputs = (hs-i8) @ (Wd-i8)^T * scales + bd, in-place ----------------
__launch_bounds__(512, 2)
__global__ void k_out(const float* __restrict__ bd, float* out) {
    int tid = threadIdx.x;
    int w = tid >> 6, l = tid & 63;
    int hi = l >> 4, lo = l & 15;
    size_t m0 = (size_t)blockIdx.x * 256 + w * 32;
    const unsigned char* hsb = (const unsigned char*)out;
    float bdv[16], sdl[16];
#pragma unroll
    for (int nt = 0; nt < 16; nt++) {
        bdv[nt] = bd[nt * 16 + lo];
        sdl[nt] = g_sd[nt * 16 + lo] * (1.f / 127.f);
    }
    i32x4 acc[2][16];
#pragma unroll
    for (int m = 0; m < 2; m++)
#pragma unroll
        for (int nt = 0; nt < 16; nt++) { acc[m][nt][0] = 0; acc[m][nt][1] = 0; acc[m][nt][2] = 0; acc[m][nt][3] = 0; }
#pragma unroll 2
    for (int kt = 0; kt < 8; kt++) {
        i32x4 a0 = *(const i32x4*)(hsb + (m0 + lo) * 1024 + kt * 64 + hi * 16);
        i32x4 a1 = *(const i32x4*)(hsb + (m0 + 16 + lo) * 1024 + kt * 64 + hi * 16);
#pragma unroll
        for (int nt = 0; nt < 16; nt++) {
            i32x4 bf = *(const i32x4*)(g_Wdq + (nt * 8 + kt) * 1024 + l * 16);
            acc[0][nt] = __builtin_amdgcn_mfma_i32_16x16x64_i8(a0, bf, acc[0][nt], 0, 0, 0);
            acc[1][nt] = __builtin_amdgcn_mfma_i32_16x16x64_i8(a1, bf, acc[1][nt], 0, 0, 0);
        }
    }
#pragma unroll
    for (int m = 0; m < 2; m++)
#pragma unroll
        for (int nt = 0; nt < 16; nt++)
#pragma unroll
            for (int rg = 0; rg < 4; rg++) {
                size_t row = m0 + m * 16 + hi * 4 + rg;
                out[row * O_ + nt * 16 + lo] = (float)acc[m][nt][rg] * sdl[nt] + bdv[nt];
            }
}

extern "C" void kernel_launch(void* const* d_in, const int* in_sizes, int n_in,
                              void* d_out, int out_size, void* d_ws, size_t ws_size,
                              hipStream_t stream) {
    const int*   x   = (const int*)d_in[0];
    const float* h0  = (const float*)d_in[1];
    const float* emb = (const float*)d_in[2];
    const float* W   = (const float*)d_in[3];
    const float* b   = (const float*)d_in[4];
    const float* Wd  = (const float*)d_in[5];
    const float* bd  = (const float*)d_in[6];
    float* out = (float*)d_out;

    k_prep8<<<dim3(H_), dim3(64), 0, stream>>>(W);
    k_prepWd8<<<dim3(O_), dim3(64), 0, stream>>>(Wd);
    k_embWx<<<dim3(V_), dim3(256), 0, stream>>>(emb, W, b);   // after k_prep8 (g_scale)
    k_rnn<<<dim3(16), dim3(512), 0, stream>>>(x, h0, out);
    k_out<<<dim3(1024), dim3(512), 0, stream>>>(bd, out);
}